// Round 1
// baseline (328.729 us; speedup 1.0000x reference)
//
#include <hip/hip_runtime.h>
#include <math.h>

#define OUT 7
#define NVOX 343  // 7*7*7

struct AxisSamp {
    int lo, hi;
    float w0, w1;
};

__device__ __forceinline__ AxisSamp axis_samp(float c, float fdim, int dim) {
    AxisSamp a;
    float valid = (c > -1.0f && c < fdim) ? 1.0f : 0.0f;
    float cc = fminf(fmaxf(c, 0.0f), fdim - 1.0f);
    int lo = (int)floorf(cc);
    int hi = min(lo + 1, dim - 1);
    float fr = cc - (float)lo;
    a.lo = lo; a.hi = hi;
    a.w0 = (1.0f - fr) * valid;
    a.w1 = fr * valid;
    return a;
}

__global__ __launch_bounds__(256) void roi_align_ms3d_kernel(
    const float* __restrict__ f0, const float* __restrict__ f1,
    const float* __restrict__ f2, const float* __restrict__ f3,
    const float* __restrict__ boxes, float* __restrict__ out,
    int N, int C, int d0, int d1, int d2_, int d3)
{
    int idx = blockIdx.x * blockDim.x + threadIdx.x;
    int total = N * C * NVOX;
    if (idx >= total) return;

    int voxel = idx % NVOX;
    int c = (idx / NVOX) % C;
    int n = idx / (NVOX * C);
    int oz = voxel % OUT;
    int oy = (voxel / OUT) % OUT;
    int ox = voxel / (OUT * OUT);

    const float* bp = boxes + n * 6;
    float b0 = bp[0], b1 = bp[1], b2 = bp[2];
    float b3 = bp[3], b4 = bp[4], b5 = bp[5];

    // level_map
    float vol = (b3 - b0) * (b4 - b1) * (b5 - b2);
    float s = cbrtf(vol);
    float lvl = floorf(4.0f + log2f(s / 160.0f) + 1e-6f);
    lvl = fminf(fmaxf(lvl, 2.0f), 5.0f);
    int l = (int)lvl - 2;

    const float* f;
    int dim;
    float scale;
    if (l == 0)      { f = f0; dim = d0;  scale = 0.25f;    }
    else if (l == 1) { f = f1; dim = d1;  scale = 0.125f;   }
    else if (l == 2) { f = f2; dim = d2_; scale = 0.0625f;  }
    else             { f = f3; dim = d3;  scale = 0.03125f; }

    float fdim = (float)dim;
    float sx = b0 * scale, sy = b1 * scale, sz = b2 * scale;
    float szx = fmaxf(b3 * scale - sx, 1.0f);
    float szy = fmaxf(b4 * scale - sy, 1.0f);
    float szz = fmaxf(b5 * scale - sz, 1.0f);
    float bx = szx * (1.0f / OUT), by = szy * (1.0f / OUT), bz = szz * (1.0f / OUT);

    AxisSamp ax[2], ay[2], az[2];
    #pragma unroll
    for (int r = 0; r < 2; ++r) {
        float off = (r + 0.5f) * 0.5f;
        ax[r] = axis_samp(sx + ((float)ox + off) * bx, fdim, dim);
        ay[r] = axis_samp(sy + ((float)oy + off) * by, fdim, dim);
        az[r] = axis_samp(sz + ((float)oz + off) * bz, fdim, dim);
    }

    const int dsq = dim * dim;
    const float* fc = f + (size_t)c * dim * dsq;

    float acc = 0.0f;
    #pragma unroll
    for (int rx = 0; rx < 2; ++rx) {
        const float* pxl = fc + ax[rx].lo * dsq;
        const float* pxh = fc + ax[rx].hi * dsq;
        float wx0 = ax[rx].w0, wx1 = ax[rx].w1;
        #pragma unroll
        for (int ry = 0; ry < 2; ++ry) {
            int ryl = ay[ry].lo * dim;
            int ryh = ay[ry].hi * dim;
            float wy0 = ay[ry].w0, wy1 = ay[ry].w1;
            #pragma unroll
            for (int rz = 0; rz < 2; ++rz) {
                int zl = az[rz].lo, zh = az[rz].hi;
                float wz0 = az[rz].w0, wz1 = az[rz].w1;

                float v000 = pxl[ryl + zl];
                float v001 = pxl[ryl + zh];
                float v010 = pxl[ryh + zl];
                float v011 = pxl[ryh + zh];
                float v100 = pxh[ryl + zl];
                float v101 = pxh[ryl + zh];
                float v110 = pxh[ryh + zl];
                float v111 = pxh[ryh + zh];

                float vx0 = wy0 * (wz0 * v000 + wz1 * v001) + wy1 * (wz0 * v010 + wz1 * v011);
                float vx1 = wy0 * (wz0 * v100 + wz1 * v101) + wy1 * (wz0 * v110 + wz1 * v111);
                acc += wx0 * vx0 + wx1 * vx1;
            }
        }
    }

    out[idx] = acc * 0.125f;
}

extern "C" void kernel_launch(void* const* d_in, const int* in_sizes, int n_in,
                              void* d_out, int out_size, void* d_ws, size_t ws_size,
                              hipStream_t stream) {
    const float* f0 = (const float*)d_in[0];
    const float* f1 = (const float*)d_in[1];
    const float* f2 = (const float*)d_in[2];
    const float* f3 = (const float*)d_in[3];
    const float* boxes = (const float*)d_in[4];
    float* out = (float*)d_out;

    int N = in_sizes[4] / 6;
    int C = out_size / (N * NVOX);

    // derive cubic dims per level from element counts
    auto cdim = [&](int sz) {
        int per_c = sz / C;
        int d = (int)(cbrtf((float)per_c) + 0.5f);
        return d;
    };
    int d0 = cdim(in_sizes[0]);
    int d1 = cdim(in_sizes[1]);
    int d2 = cdim(in_sizes[2]);
    int d3 = cdim(in_sizes[3]);

    int total = N * C * NVOX;
    int block = 256;
    int grid = (total + block - 1) / block;
    roi_align_ms3d_kernel<<<grid, block, 0, stream>>>(f0, f1, f2, f3, boxes, out,
                                                      N, C, d0, d1, d2, d3);
}